// Round 5
// baseline (141.178 us; speedup 1.0000x reference)
//
#include <hip/hip_runtime.h>

// entmax-1.5 over rows of [R=16384, N=4096] fp32.
// tau* solves f(tau) = sum_i [z_i - tau]_+^2 = 1 with z = (x - max)/2, so
// z_max = 0 and tau* in [-1, 0). Newton from tau = -1 is monotone from the
// left (f convex, decreasing).
// Pruning fact: every Newton iterate stays in [-1, tau*], so only elements
// with z > -1 (x > max - 2) ever contribute: ~120 of 4096 for Gaussian rows.
// So NO full-width Newton passes are needed -- prune immediately at tau=-1.
// Three full-width passes total (compiler remats x from L2 between passes;
// that is cheaper than holding 64 VGPRs of row data):
//   A. row max (lane tree + 64-lane butterfly)
//   B. ballot-compaction of survivors s = z+1 > 0 into wave-private LDS
//      (single pass: v_cmp -> ballot -> mbcnt position, running base)
//   C. final p = [z - tau]_+^2 * inv, nontemporal float4 store (write-once
//      data bypasses cache so the 256 MiB input stays L3-resident)
// Newton runs on <=4 survivor registers/lane, tp = tau+1 in [0,1),
// breaking on |dtau| < 1e-7 (g floors at fp32 noise; dtau does not).
// Normalizer = s2 from the last iteration (exact: non-survivors are 0).

#define ROWLEN 4096
#define CHUNKS 16   // float4 per lane per pass
#define RPB 4       // rows (waves) per block
#define CAP 256     // survivor capacity per wave
#define SLOTS 4     // CAP / 64

typedef float f4 __attribute__((ext_vector_type(4)));

__global__ __launch_bounds__(256) void entmax15_kernel(
    const float* __restrict__ x, float* __restrict__ out, int rows) {
    __shared__ float sv[RPB][CAP];  // wave-private, no barriers needed
    const int wave = threadIdx.x >> 6;
    const int lane = threadIdx.x & 63;
    const int row = blockIdx.x * RPB + wave;
    if (row >= rows) return;  // wave-uniform

    const float* __restrict__ xr = x + (size_t)row * ROWLEN;
    float* __restrict__ orow = out + (size_t)row * ROWLEN;

    // ---- Pass A: row max ----
    float m = -3.4e38f;
    #pragma unroll
    for (int k = 0; k < CHUNKS; ++k) {
        const float4 v = *reinterpret_cast<const float4*>(xr + (size_t)(k * 64 + lane) * 4);
        m = fmaxf(m, fmaxf(fmaxf(v.x, v.y), fmaxf(v.z, v.w)));
    }
    #pragma unroll
    for (int s = 1; s < 64; s <<= 1) m = fmaxf(m, __shfl_xor(m, s, 64));
    // s_i = z_i + 1 = fmaf(x_i, 0.5, c2); survivor iff s_i > 0
    const float c2 = fmaf(m, -0.5f, 1.0f);

    // ---- Pass B: ballot-compact survivors into LDS (values only) ----
    const unsigned long long lt = (1ull << lane) - 1ull;  // lanes below me
    int base = 0;
    #pragma unroll
    for (int k = 0; k < CHUNKS; ++k) {
        const float4 v = *reinterpret_cast<const float4*>(xr + (size_t)(k * 64 + lane) * 4);
        float e[4] = {fmaf(v.x, 0.5f, c2), fmaf(v.y, 0.5f, c2),
                      fmaf(v.z, 0.5f, c2), fmaf(v.w, 0.5f, c2)};
        #pragma unroll
        for (int j = 0; j < 4; ++j) {
            const bool p = e[j] > 0.0f;
            const unsigned long long mb = __ballot(p);
            if (p) {
                const int pos = base + __popcll(mb & lt);
                if (pos < CAP) sv[wave][pos] = e[j];
            }
            base += __popcll(mb);  // wave-uniform
        }
    }
    const int K = base;  // total survivors (>= 1: the max element has s = 1)

    float tp = 0.0f, s2f = 1.0f;  // tp = tau + 1 in [0, 1)
    if (K <= CAP) {
        // ---- Newton on <= 4 survivor registers per lane ----
        float r[SLOTS];
        #pragma unroll
        for (int j = 0; j < SLOTS; ++j) {
            const int q = lane + 64 * j;
            r[j] = (q < K) ? sv[wave][q] : -1.0f;  // pad: fmax(-1-tp,0) = 0
        }
        for (int it = 0; it < 16; ++it) {
            float s1 = 0.0f, s2 = 0.0f;
            #pragma unroll
            for (int j = 0; j < SLOTS; ++j) {
                const float t = fmaxf(r[j] - tp, 0.0f);
                s1 += t;
                s2 = fmaf(t, t, s2);
            }
            #pragma unroll
            for (int s = 1; s < 64; s <<= 1) {
                s1 += __shfl_xor(s1, s, 64);
                s2 += __shfl_xor(s2, s, 64);
            }
            const float dtau = (s2 - 1.0f) / fmaxf(2.0f * s1, 1e-20f);
            s2f = s2;
            tp += dtau;
            if (fabsf(dtau) < 1e-7f) break;  // wave-uniform (identical tree)
        }
    } else {
        // ---- Fallback (degenerate rows): full-width Newton from L2 ----
        for (int it = 0; it < 25; ++it) {
            const float c = c2 - tp;
            float s1 = 0.0f, s2 = 0.0f;
            #pragma unroll
            for (int k = 0; k < CHUNKS; ++k) {
                const float4 v = *reinterpret_cast<const float4*>(xr + (size_t)(k * 64 + lane) * 4);
                float t;
                t = fmaxf(fmaf(v.x, 0.5f, c), 0.0f); s1 += t; s2 = fmaf(t, t, s2);
                t = fmaxf(fmaf(v.y, 0.5f, c), 0.0f); s1 += t; s2 = fmaf(t, t, s2);
                t = fmaxf(fmaf(v.z, 0.5f, c), 0.0f); s1 += t; s2 = fmaf(t, t, s2);
                t = fmaxf(fmaf(v.w, 0.5f, c), 0.0f); s1 += t; s2 = fmaf(t, t, s2);
            }
            #pragma unroll
            for (int s = 1; s < 64; s <<= 1) {
                s1 += __shfl_xor(s1, s, 64);
                s2 += __shfl_xor(s2, s, 64);
            }
            const float dtau = (s2 - 1.0f) / fmaxf(2.0f * s1, 1e-20f);
            s2f = s2;
            tp += dtau;
            if (fabsf(dtau) < 1e-7f) break;
        }
    }

    const float inv = 1.0f / (s2f + 1e-8f);
    const float cF = c2 - tp;  // t_i = fmaf(x_i, 0.5, cF) = z_i - tau

    // ---- Pass C: dense output, nontemporal float4 ----
    #pragma unroll
    for (int k = 0; k < CHUNKS; ++k) {
        const float4 v = *reinterpret_cast<const float4*>(xr + (size_t)(k * 64 + lane) * 4);
        f4 o;
        float t;
        t = fmaxf(fmaf(v.x, 0.5f, cF), 0.0f); o.x = t * t * inv;
        t = fmaxf(fmaf(v.y, 0.5f, cF), 0.0f); o.y = t * t * inv;
        t = fmaxf(fmaf(v.z, 0.5f, cF), 0.0f); o.z = t * t * inv;
        t = fmaxf(fmaf(v.w, 0.5f, cF), 0.0f); o.w = t * t * inv;
        __builtin_nontemporal_store(o, reinterpret_cast<f4*>(orow + (size_t)(k * 64 + lane) * 4));
    }
}

extern "C" void kernel_launch(void* const* d_in, const int* in_sizes, int n_in,
                              void* d_out, int out_size, void* d_ws, size_t ws_size,
                              hipStream_t stream) {
    const float* x = (const float*)d_in[0];
    float* out = (float*)d_out;
    const int rows = in_sizes[0] / ROWLEN;  // 16384
    const int blocks = (rows + RPB - 1) / RPB;
    entmax15_kernel<<<blocks, 256, 0, stream>>>(x, out, rows);
}

// Round 6
// 107.958 us; speedup vs baseline: 1.3077x; 1.3077x over previous
//
#include <hip/hip_runtime.h>

// entmax-1.5 over rows of [R=16384, N=4096] fp32.
// tau* solves f(tau) = sum_i [z_i - tau]_+^2 = 1 with z = (x - max)/2, so
// z_max = 0, tau* in [-1, 0). Newton from tau = -1 is monotone from the left
// (f convex decreasing). Only elements with z > -1 (x > max - 2) can ever
// contribute (~120/4096 Gaussian) -> prune immediately, solve on registers.
// Structure: one wave per row pair (2-row software pipeline):
//   load A (16 float4) ; issue load B ; sched_barrier  -> B streams during A
//   process A: butterfly max, ballot-compact survivors into wave-private LDS,
//              Newton on <=4 regs/lane (|dtau|<1e-7 break, ~5 iters),
//              normalizer = last s2 (exact), dense NT float4 store from regs
//   process B identically.
// NT stores keep the 256 MiB input L3-resident across graph replays
// (R4 evidence: FETCH 131 MB = half-input from HBM).

#define ROWLEN 4096
#define ELEMS 64
#define CHUNKS 16
#define RPB 4       // waves per block
#define CAP 256     // survivor capacity per wave
#define SLOTS 4     // CAP / 64

typedef float f4 __attribute__((ext_vector_type(4)));

__device__ __forceinline__ void process_row(const float* __restrict__ z,  // 64 regs
                                            float* __restrict__ orow,
                                            float* __restrict__ svw,
                                            int lane) {
    // ---- Row max: lane tree + 64-lane butterfly ----
    float m = z[0];
    #pragma unroll
    for (int i = 1; i < ELEMS; ++i) m = fmaxf(m, z[i]);
    #pragma unroll
    for (int s = 1; s < 64; s <<= 1) m = fmaxf(m, __shfl_xor(m, s, 64));
    const float c2 = fmaf(m, -0.5f, 1.0f);  // s_i = fmaf(x,0.5,c2) = z_i + 1

    // ---- Ballot-compact survivors (s_i > 0) into wave-private LDS ----
    const unsigned long long lt = (1ull << lane) - 1ull;
    int base = 0;
    #pragma unroll
    for (int i = 0; i < ELEMS; ++i) {
        const float e = fmaf(z[i], 0.5f, c2);
        const bool p = e > 0.0f;
        const unsigned long long mb = __ballot(p);
        if (p) {
            const int pos = base + __popcll(mb & lt);
            if (pos < CAP) svw[pos] = e;
        }
        base += __popcll(mb);  // wave-uniform
    }
    const int K = base;  // >= 1 (max element has s = 1)

    float tp = 0.0f, s2f = 1.0f;  // tp = tau + 1 in [0, 1)
    if (K <= CAP) {
        // ---- Newton on <= SLOTS survivor registers per lane ----
        float r[SLOTS];
        #pragma unroll
        for (int j = 0; j < SLOTS; ++j) {
            const int q = lane + 64 * j;
            r[j] = (q < K) ? svw[q] : -1.0f;  // pad: fmax(-1-tp,0) = 0
        }
        for (int it = 0; it < 16; ++it) {
            float s1 = 0.0f, s2 = 0.0f;
            #pragma unroll
            for (int j = 0; j < SLOTS; ++j) {
                const float t = fmaxf(r[j] - tp, 0.0f);
                s1 += t;
                s2 = fmaf(t, t, s2);
            }
            #pragma unroll
            for (int s = 1; s < 64; s <<= 1) {
                s1 += __shfl_xor(s1, s, 64);
                s2 += __shfl_xor(s2, s, 64);
            }
            const float dtau = (s2 - 1.0f) / fmaxf(2.0f * s1, 1e-20f);
            s2f = s2;
            tp += dtau;
            if (fabsf(dtau) < 1e-7f) break;  // wave-uniform (identical tree)
        }
    } else {
        // ---- Fallback (degenerate rows): full-width Newton from registers ----
        for (int it = 0; it < 25; ++it) {
            const float c = c2 - tp;
            float s1 = 0.0f, s2 = 0.0f;
            #pragma unroll
            for (int i = 0; i < ELEMS; ++i) {
                const float t = fmaxf(fmaf(z[i], 0.5f, c), 0.0f);
                s1 += t;
                s2 = fmaf(t, t, s2);
            }
            #pragma unroll
            for (int s = 1; s < 64; s <<= 1) {
                s1 += __shfl_xor(s1, s, 64);
                s2 += __shfl_xor(s2, s, 64);
            }
            const float dtau = (s2 - 1.0f) / fmaxf(2.0f * s1, 1e-20f);
            s2f = s2;
            tp += dtau;
            if (fabsf(dtau) < 1e-7f) break;
        }
    }

    const float inv = 1.0f / (s2f + 1e-8f);
    const float cF = c2 - tp;  // t_i = fmaf(x_i, 0.5, cF) = z_i - tau

    // ---- Dense output from registers, nontemporal float4 ----
    #pragma unroll
    for (int k = 0; k < CHUNKS; ++k) {
        f4 o;
        float t;
        t = fmaxf(fmaf(z[4 * k + 0], 0.5f, cF), 0.0f); o.x = t * t * inv;
        t = fmaxf(fmaf(z[4 * k + 1], 0.5f, cF), 0.0f); o.y = t * t * inv;
        t = fmaxf(fmaf(z[4 * k + 2], 0.5f, cF), 0.0f); o.z = t * t * inv;
        t = fmaxf(fmaf(z[4 * k + 3], 0.5f, cF), 0.0f); o.w = t * t * inv;
        __builtin_nontemporal_store(o, reinterpret_cast<f4*>(orow + (size_t)(k * 64 + lane) * 4));
    }
}

__global__ __launch_bounds__(256, 3) void entmax15_kernel(
    const float* __restrict__ x, float* __restrict__ out, int rows) {
    __shared__ float sv[RPB][CAP];  // wave-private, no barriers
    const int wave = threadIdx.x >> 6;
    const int lane = threadIdx.x & 63;
    const int wid = blockIdx.x * RPB + wave;
    const int r0 = 2 * wid;
    const int r1 = r0 + 1;
    if (r0 >= rows) return;  // wave-uniform

    const float* __restrict__ xr0 = x + (size_t)r0 * ROWLEN;
    const bool hasB = (r1 < rows);
    const float* __restrict__ xr1 = x + (size_t)(hasB ? r1 : r0) * ROWLEN;

    // ---- Load row A; immediately issue row B's loads (prefetch in flight) ----
    float za[ELEMS], zb[ELEMS];
    #pragma unroll
    for (int k = 0; k < CHUNKS; ++k) {
        const f4 v = *reinterpret_cast<const f4*>(xr0 + (size_t)(k * 64 + lane) * 4);
        za[4 * k + 0] = v.x; za[4 * k + 1] = v.y;
        za[4 * k + 2] = v.z; za[4 * k + 3] = v.w;
    }
    #pragma unroll
    for (int k = 0; k < CHUNKS; ++k) {
        const f4 v = *reinterpret_cast<const f4*>(xr1 + (size_t)(k * 64 + lane) * 4);
        zb[4 * k + 0] = v.x; zb[4 * k + 1] = v.y;
        zb[4 * k + 2] = v.z; zb[4 * k + 3] = v.w;
    }
    __builtin_amdgcn_sched_barrier(0);  // pin load issue above A's compute

    process_row(za, out + (size_t)r0 * ROWLEN, sv[wave], lane);
    if (hasB) process_row(zb, out + (size_t)r1 * ROWLEN, sv[wave], lane);
}

extern "C" void kernel_launch(void* const* d_in, const int* in_sizes, int n_in,
                              void* d_out, int out_size, void* d_ws, size_t ws_size,
                              hipStream_t stream) {
    const float* x = (const float*)d_in[0];
    float* out = (float*)d_out;
    const int rows = in_sizes[0] / ROWLEN;   // 16384
    const int pairs = (rows + 1) / 2;        // 8192
    const int blocks = (pairs + RPB - 1) / RPB;  // 2048
    entmax15_kernel<<<blocks, 256, 0, stream>>>(x, out, rows);
}

// Round 7
// 95.737 us; speedup vs baseline: 1.4746x; 1.1277x over previous
//
#include <hip/hip_runtime.h>

// entmax-1.5 over rows of [R=16384, N=4096] fp32.
// tau* solves f(tau) = sum_i [z_i - tau]_+^2 = 1 with z = (x - max)/2, so
// z_max = 0 and tau* in [-1, 0). Newton from tau = -1 converges monotonically
// from the left (f convex, decreasing). Every iterate stays in [-1, tau*], so
// only elements with z > -1 (x > max - 2) ever contribute (~120/4096 for
// Gaussian rows): prune IMMEDIATELY at tau = -1, no full-width Newton needed.
//
// Winning structure (R4 evidence, 75 us): one wave per row; load the row into
// z[64] registers ONCE architecturally; compiler remats from L1/L2 as needed.
// Per wave: (1) max: lane tree + 6-step butterfly; (2) ballot-compact
// survivors s = z+1 > 0 into wave-private LDS; (3) Newton on <=4 survivor
// regs/lane, |dtau| < 1e-7 break (~5 iters), normalizer = last s2 (exact,
// non-survivors contribute 0); (4) dense nontemporal float4 store (write-once
// output bypasses cache -> input stays half-L3-resident; FETCH 131 MB).

#define ROWLEN 4096
#define ELEMS 64
#define CHUNKS 16
#define RPB 4       // waves (rows) per block
#define CAP 256     // survivor capacity per wave
#define SLOTS 4     // CAP / 64

typedef float f4 __attribute__((ext_vector_type(4)));

__global__ __launch_bounds__(256) void entmax15_kernel(
    const float* __restrict__ x, float* __restrict__ out, int rows) {
    __shared__ float sv[RPB][CAP];  // wave-private, no barriers
    const int wave = threadIdx.x >> 6;
    const int lane = threadIdx.x & 63;
    const int row = blockIdx.x * RPB + wave;
    if (row >= rows) return;  // wave-uniform

    const float* __restrict__ xr = x + (size_t)row * ROWLEN;
    float* __restrict__ orow = out + (size_t)row * ROWLEN;
    float* __restrict__ svw = sv[wave];

    // ---- Single architectural load of the row ----
    float z[ELEMS];
    #pragma unroll
    for (int k = 0; k < CHUNKS; ++k) {
        const f4 v = *reinterpret_cast<const f4*>(xr + (size_t)(k * 64 + lane) * 4);
        z[4 * k + 0] = v.x; z[4 * k + 1] = v.y;
        z[4 * k + 2] = v.z; z[4 * k + 3] = v.w;
    }

    // ---- Pass 1: row max ----
    float m = z[0];
    #pragma unroll
    for (int i = 1; i < ELEMS; ++i) m = fmaxf(m, z[i]);
    #pragma unroll
    for (int s = 1; s < 64; s <<= 1) m = fmaxf(m, __shfl_xor(m, s, 64));
    const float c2 = fmaf(m, -0.5f, 1.0f);  // s_i = fmaf(x_i,0.5,c2) = z_i + 1

    // ---- Pass 2: ballot-compact survivors (s_i > 0) into LDS ----
    const unsigned long long lt = (1ull << lane) - 1ull;
    int base = 0;
    #pragma unroll
    for (int i = 0; i < ELEMS; ++i) {
        const float e = fmaf(z[i], 0.5f, c2);
        const bool p = e > 0.0f;
        const unsigned long long mb = __ballot(p);
        if (p) {
            const int pos = base + __popcll(mb & lt);
            if (pos < CAP) svw[pos] = e;
        }
        base += __popcll(mb);  // wave-uniform
    }
    const int K = base;  // >= 1 (the max element has s = 1)

    float tp = 0.0f, s2f = 1.0f;  // tp = tau + 1 in [0, 1)
    if (K <= CAP) {
        // ---- Newton on <= SLOTS survivor registers per lane ----
        float r[SLOTS];
        #pragma unroll
        for (int j = 0; j < SLOTS; ++j) {
            const int q = lane + 64 * j;
            r[j] = (q < K) ? svw[q] : -1.0f;  // pad: fmax(-1-tp,0) = 0
        }
        for (int it = 0; it < 16; ++it) {
            float s1 = 0.0f, s2 = 0.0f;
            #pragma unroll
            for (int j = 0; j < SLOTS; ++j) {
                const float t = fmaxf(r[j] - tp, 0.0f);
                s1 += t;
                s2 = fmaf(t, t, s2);
            }
            #pragma unroll
            for (int s = 1; s < 64; s <<= 1) {
                s1 += __shfl_xor(s1, s, 64);
                s2 += __shfl_xor(s2, s, 64);
            }
            const float dtau = (s2 - 1.0f) / fmaxf(2.0f * s1, 1e-20f);
            s2f = s2;
            tp += dtau;
            if (fabsf(dtau) < 1e-7f) break;  // wave-uniform (identical tree)
        }
    } else {
        // ---- Fallback (degenerate rows): full-width Newton from z regs ----
        for (int it = 0; it < 25; ++it) {
            const float c = c2 - tp;
            float s1 = 0.0f, s2 = 0.0f;
            #pragma unroll
            for (int i = 0; i < ELEMS; ++i) {
                const float t = fmaxf(fmaf(z[i], 0.5f, c), 0.0f);
                s1 += t;
                s2 = fmaf(t, t, s2);
            }
            #pragma unroll
            for (int s = 1; s < 64; s <<= 1) {
                s1 += __shfl_xor(s1, s, 64);
                s2 += __shfl_xor(s2, s, 64);
            }
            const float dtau = (s2 - 1.0f) / fmaxf(2.0f * s1, 1e-20f);
            s2f = s2;
            tp += dtau;
            if (fabsf(dtau) < 1e-7f) break;
        }
    }

    const float inv = 1.0f / (s2f + 1e-8f);
    const float cF = c2 - tp;  // t_i = fmaf(x_i, 0.5, cF) = z_i - tau

    // ---- Pass 3: dense output from registers, nontemporal float4 ----
    #pragma unroll
    for (int k = 0; k < CHUNKS; ++k) {
        f4 o;
        float t;
        t = fmaxf(fmaf(z[4 * k + 0], 0.5f, cF), 0.0f); o.x = t * t * inv;
        t = fmaxf(fmaf(z[4 * k + 1], 0.5f, cF), 0.0f); o.y = t * t * inv;
        t = fmaxf(fmaf(z[4 * k + 2], 0.5f, cF), 0.0f); o.z = t * t * inv;
        t = fmaxf(fmaf(z[4 * k + 3], 0.5f, cF), 0.0f); o.w = t * t * inv;
        __builtin_nontemporal_store(o, reinterpret_cast<f4*>(orow + (size_t)(k * 64 + lane) * 4));
    }
}

extern "C" void kernel_launch(void* const* d_in, const int* in_sizes, int n_in,
                              void* d_out, int out_size, void* d_ws, size_t ws_size,
                              hipStream_t stream) {
    const float* x = (const float*)d_in[0];
    float* out = (float*)d_out;
    const int rows = in_sizes[0] / ROWLEN;       // 16384
    const int blocks = (rows + RPB - 1) / RPB;   // 4096
    entmax15_kernel<<<blocks, 256, 0, stream>>>(x, out, rows);
}

// Round 9
// 89.944 us; speedup vs baseline: 1.5696x; 1.0644x over previous
//
#include <hip/hip_runtime.h>

// entmax-1.5 over rows of [R=16384, N=4096] fp32.
// tau* solves f(tau) = sum_i [z_i - tau]_+^2 = 1 with z = (x - max)/2, so
// z_max = 0 and tau* in [-1, 0). Newton from tau = -1 is monotone from the
// left (f convex, decreasing); every iterate stays in [-1, tau*], so only
// elements with z > -1 (x > max - 2) ever contribute (~180/4096 Gaussian).
// s-space: s_i = z_i + 1 = fma(x_i, 0.5, c2), tp = tau + 1 in [0, 1).
//
// Proven components only (R4 numerics + R8 compaction):
//  - one wave per row, single architectural load of z[64] (R4: FETCH 131 MB)
//  - per-lane-strip compaction at tau = -1: each lane stores its own
//    survivors (E ~ 2.8, cap 16) in a private LDS strip; NO cross-lane ops
//    except one overflow ballot (R7 lesson: serial cross-lane rounds are
//    the scarce resource; R4's count+scan+2 full Newtons all deleted)
//  - plain Newton on 16 survivor regs/lane, |dtau| < 1e-7 break (~7 iters),
//    normalizer = last s2 (exact: non-survivors contribute 0)  [R4-proven]
//  - dense NT float4 store from regs (write-once output bypasses cache ->
//    input stays half-L3-resident across replays)               [R4-proven]
//  - full-width-Newton fallback if any lane exceeds 16 survivors

#define ROWLEN 4096
#define ELEMS 64
#define CHUNKS 16
#define RPB 4        // waves (rows) per block
#define NSLOT 16     // survivor slots per lane
#define LSTRIDE 20   // floats; 80 B: keeps 16B alignment, spreads banks

typedef float f4 __attribute__((ext_vector_type(4)));

__global__ __launch_bounds__(256) void entmax15_kernel(
    const float* __restrict__ x, float* __restrict__ out, int rows) {
    __shared__ float sv[RPB][64 * LSTRIDE];  // wave-private, no barriers
    const int wave = threadIdx.x >> 6;
    const int lane = threadIdx.x & 63;
    const int row = blockIdx.x * RPB + wave;
    if (row >= rows) return;  // wave-uniform

    const float* __restrict__ xr = x + (size_t)row * ROWLEN;
    float* __restrict__ orow = out + (size_t)row * ROWLEN;
    float* __restrict__ svl = &sv[wave][lane * LSTRIDE];

    // ---- Single architectural load of the row ----
    float z[ELEMS];
    #pragma unroll
    for (int k = 0; k < CHUNKS; ++k) {
        const f4 v = *reinterpret_cast<const f4*>(xr + (size_t)(k * 64 + lane) * 4);
        z[4 * k + 0] = v.x; z[4 * k + 1] = v.y;
        z[4 * k + 2] = v.z; z[4 * k + 3] = v.w;
    }

    // ---- Pass 1: row max (lane tree + 6-step butterfly) ----
    float m = z[0];
    #pragma unroll
    for (int i = 1; i < ELEMS; ++i) m = fmaxf(m, z[i]);
    #pragma unroll
    for (int s = 1; s < 64; s <<= 1) m = fmaxf(m, __shfl_xor(m, s, 64));
    const float c2 = fmaf(m, -0.5f, 1.0f);  // s_i = fmaf(x_i, 0.5, c2) = z_i + 1

    // ---- Pass 2: per-lane compaction into private LDS strip ----
    const f4 neg1 = {-1.0f, -1.0f, -1.0f, -1.0f};
    #pragma unroll
    for (int j = 0; j < NSLOT / 4; ++j)
        *reinterpret_cast<f4*>(svl + 4 * j) = neg1;
    int c = 0;
    #pragma unroll
    for (int i = 0; i < ELEMS; ++i) {
        const float e = fmaf(z[i], 0.5f, c2);
        if (e > 0.0f) {
            if (c < NSLOT) svl[c] = e;
            ++c;
        }
    }
    const bool ovf = (__ballot(c > NSLOT) != 0ull);  // only cross-lane op here

    float tp = 0.0f, s2f = 1.0f;  // tp = tau + 1 in [0, 1)
    if (!ovf) {
        // ---- Read back survivors; pads (-1) contribute 0 for tp >= 0 ----
        float r[NSLOT];
        #pragma unroll
        for (int j = 0; j < NSLOT / 4; ++j) {
            const f4 v = *reinterpret_cast<const f4*>(svl + 4 * j);
            r[4 * j + 0] = v.x; r[4 * j + 1] = v.y;
            r[4 * j + 2] = v.z; r[4 * j + 3] = v.w;
        }
        // ---- Plain Newton (R4-proven numerics), ~7 iters from tp = 0 ----
        for (int it = 0; it < 16; ++it) {
            float s1 = 0.0f, s2 = 0.0f;
            #pragma unroll
            for (int j = 0; j < NSLOT; ++j) {
                const float t = fmaxf(r[j] - tp, 0.0f);
                s1 += t;
                s2 = fmaf(t, t, s2);
            }
            #pragma unroll
            for (int s = 1; s < 64; s <<= 1) {
                s1 += __shfl_xor(s1, s, 64);
                s2 += __shfl_xor(s2, s, 64);
            }
            const float dtau = (s2 - 1.0f) / fmaxf(2.0f * s1, 1e-20f);
            s2f = s2;
            tp += dtau;
            if (fabsf(dtau) < 1e-7f) break;  // wave-uniform (identical tree)
        }
    } else {
        // ---- Fallback (degenerate rows): full-width Newton from z regs ----
        for (int it = 0; it < 25; ++it) {
            const float cc = c2 - tp;
            float s1 = 0.0f, s2 = 0.0f;
            #pragma unroll
            for (int i = 0; i < ELEMS; ++i) {
                const float t = fmaxf(fmaf(z[i], 0.5f, cc), 0.0f);
                s1 += t;
                s2 = fmaf(t, t, s2);
            }
            #pragma unroll
            for (int s = 1; s < 64; s <<= 1) {
                s1 += __shfl_xor(s1, s, 64);
                s2 += __shfl_xor(s2, s, 64);
            }
            const float dtau = (s2 - 1.0f) / fmaxf(2.0f * s1, 1e-20f);
            s2f = s2;
            tp += dtau;
            if (fabsf(dtau) < 1e-7f) break;
        }
    }

    const float inv = 1.0f / (s2f + 1e-8f);
    const float cF = c2 - tp;  // t_i = fmaf(x_i, 0.5, cF) = z_i - tau

    // ---- Pass 3: dense output from registers, nontemporal float4 ----
    #pragma unroll
    for (int k = 0; k < CHUNKS; ++k) {
        f4 o;
        float t;
        t = fmaxf(fmaf(z[4 * k + 0], 0.5f, cF), 0.0f); o.x = t * t * inv;
        t = fmaxf(fmaf(z[4 * k + 1], 0.5f, cF), 0.0f); o.y = t * t * inv;
        t = fmaxf(fmaf(z[4 * k + 2], 0.5f, cF), 0.0f); o.z = t * t * inv;
        t = fmaxf(fmaf(z[4 * k + 3], 0.5f, cF), 0.0f); o.w = t * t * inv;
        __builtin_nontemporal_store(o, reinterpret_cast<f4*>(orow + (size_t)(k * 64 + lane) * 4));
    }
}

extern "C" void kernel_launch(void* const* d_in, const int* in_sizes, int n_in,
                              void* d_out, int out_size, void* d_ws, size_t ws_size,
                              hipStream_t stream) {
    const float* x = (const float*)d_in[0];
    float* out = (float*)d_out;
    const int rows = in_sizes[0] / ROWLEN;       // 16384
    const int blocks = (rows + RPB - 1) / RPB;   // 4096
    entmax15_kernel<<<blocks, 256, 0, stream>>>(x, out, rows);
}

// Round 10
// 75.601 us; speedup vs baseline: 1.8674x; 1.1897x over previous
//
#include <hip/hip_runtime.h>

// entmax-1.5 over rows of [R=16384, N=4096] fp32.  [R4 — proven best, 75.3 us]
// tau* solves f(tau) = sum_i [z_i - tau]_+^2 = 1 with z = (x - max)/2, so
// z_max = 0 and tau* in [-1,0). Newton from tau=-1 approaches the root
// monotonically from the left (f convex decreasing), quadratic convergence.
// One wave per row, single architectural load (compiler remats from L1/L2;
// HBM sees ~131 MB of the 256 MiB input thanks to NT-store L3 residency):
//   1. load x -> z[64] regs; max via 6-step butterfly
//   2. two full-width Newton iterations (1 fma + 1 fmax per element)
//   3. count+scan survivors (z > tau2); compact values into wave-private LDS
//   4. Newton on <=4 survivor regs/lane, break on |dtau| < 1e-7 (~5 iters)
//   5. normalizer = last s2 (exact: non-survivors contribute 0)
//   6. dense nontemporal float4 write (write-once output bypasses cache so
//      the input stays half-L3-resident across graph replays)
// Five restructures (R5-R9: earlier pruning, row pairing, ballot compaction,
// per-lane strips) all regressed: full-width VALU passes are cheap and
// overlappable; serial cross-lane rounds and lost occupancy are not.

#define ROWLEN 4096
#define ELEMS 64
#define CHUNKS 16
#define RPB 4
#define CAP 256
#define SLOTS 4

typedef float f4 __attribute__((ext_vector_type(4)));

__global__ __launch_bounds__(256) void entmax15_kernel(
    const float* __restrict__ x, float* __restrict__ out, int rows) {
    __shared__ float sv[RPB][CAP];  // wave-private survivor values, no barriers
    const int wave = threadIdx.x >> 6;
    const int lane = threadIdx.x & 63;
    const int row = blockIdx.x * RPB + wave;
    if (row >= rows) return;  // wave-uniform

    const float* __restrict__ xr = x + (size_t)row * ROWLEN;
    float* __restrict__ orow = out + (size_t)row * ROWLEN;

    // ---- Load row into registers (only HBM read of x) ----
    float z[ELEMS];
    #pragma unroll
    for (int k = 0; k < CHUNKS; ++k) {
        const float4 v = *reinterpret_cast<const float4*>(xr + (size_t)(k * 64 + lane) * 4);
        z[4 * k + 0] = v.x;
        z[4 * k + 1] = v.y;
        z[4 * k + 2] = v.z;
        z[4 * k + 3] = v.w;
    }

    // ---- Row max ----
    float m = z[0];
    #pragma unroll
    for (int i = 1; i < ELEMS; ++i) m = fmaxf(m, z[i]);
    #pragma unroll
    for (int s = 1; s < 64; s <<= 1) m = fmaxf(m, __shfl_xor(m, s, 64));
    const float mh = m * 0.5f;  // z_i - tau = fmaf(x_i, 0.5, -mh - tau)

    // ---- Two full-width Newton iterations from tau = -1 ----
    float tau = -1.0f;
    #pragma unroll
    for (int it = 0; it < 2; ++it) {
        const float c = -mh - tau;
        float s1 = 0.0f, s2 = 0.0f;
        #pragma unroll
        for (int i = 0; i < ELEMS; ++i) {
            const float t = fmaxf(fmaf(z[i], 0.5f, c), 0.0f);
            s1 += t;
            s2 = fmaf(t, t, s2);
        }
        #pragma unroll
        for (int s = 1; s < 64; s <<= 1) {
            s1 += __shfl_xor(s1, s, 64);
            s2 += __shfl_xor(s2, s, 64);
        }
        tau += (s2 - 1.0f) / fmaxf(2.0f * s1, 1e-20f);
    }
    const float c2 = -mh - tau;
    const float xcut = -2.0f * c2;  // survivor iff x > xcut  (<=> z - tau2 > 0)

    // ---- Count + exclusive scan ----
    int cnt = 0;
    #pragma unroll
    for (int i = 0; i < ELEMS; ++i) cnt += (z[i] > xcut) ? 1 : 0;
    int pre = cnt;
    #pragma unroll
    for (int s = 1; s < 64; s <<= 1) {
        const int t = __shfl_up(pre, s, 64);
        if (lane >= s) pre += t;
    }
    const int K = __shfl(pre, 63, 64);  // wave-uniform (>=1: max element survives)

    float tauF, inv;
    if (K <= CAP) {
        // ---- Compact survivor values (order irrelevant) into LDS ----
        int idx = pre - cnt;
        #pragma unroll
        for (int i = 0; i < ELEMS; ++i) {
            if (z[i] > xcut) { sv[wave][idx] = fmaf(z[i], 0.5f, c2); ++idx; }
        }
        float r[SLOTS];
        #pragma unroll
        for (int j = 0; j < SLOTS; ++j) {
            const int q = lane + 64 * j;
            r[j] = (q < K) ? sv[wave][q] : -1.0f;  // pad contributes 0 for tp >= 0
        }
        // ---- Newton on survivors, tp = tau - tau2 >= 0 ----
        float tp = 0.0f, s2f = 1.0f;
        for (int it = 0; it < 10; ++it) {
            float s1 = 0.0f, s2 = 0.0f;
            #pragma unroll
            for (int j = 0; j < SLOTS; ++j) {
                const float t = fmaxf(r[j] - tp, 0.0f);
                s1 += t;
                s2 = fmaf(t, t, s2);
            }
            #pragma unroll
            for (int s = 1; s < 64; s <<= 1) {
                s1 += __shfl_xor(s1, s, 64);
                s2 += __shfl_xor(s2, s, 64);
            }
            const float dtau = (s2 - 1.0f) / fmaxf(2.0f * s1, 1e-20f);
            s2f = s2;
            tp += dtau;
            if (fabsf(dtau) < 1e-7f) break;  // wave-uniform (identical reduce tree)
        }
        tauF = tau + tp;
        inv = 1.0f / (s2f + 1e-8f);
    } else {
        // ---- Fallback (adversarial rows): continue full-width from regs ----
        float s2f = 1.0f;
        for (int it = 0; it < 20; ++it) {
            const float c = -mh - tau;
            float s1 = 0.0f, s2 = 0.0f;
            #pragma unroll
            for (int i = 0; i < ELEMS; ++i) {
                const float t = fmaxf(fmaf(z[i], 0.5f, c), 0.0f);
                s1 += t;
                s2 = fmaf(t, t, s2);
            }
            #pragma unroll
            for (int s = 1; s < 64; s <<= 1) {
                s1 += __shfl_xor(s1, s, 64);
                s2 += __shfl_xor(s2, s, 64);
            }
            const float dtau = (s2 - 1.0f) / fmaxf(2.0f * s1, 1e-20f);
            s2f = s2;
            tau += dtau;
            if (fabsf(dtau) < 1e-7f) break;
        }
        tauF = tau;
        inv = 1.0f / (s2f + 1e-8f);
    }

    // ---- Dense output from registers, nontemporal (write-once) ----
    const float cF = -mh - tauF;
    #pragma unroll
    for (int k = 0; k < CHUNKS; ++k) {
        f4 o;
        float t;
        t = fmaxf(fmaf(z[4 * k + 0], 0.5f, cF), 0.0f); o.x = t * t * inv;
        t = fmaxf(fmaf(z[4 * k + 1], 0.5f, cF), 0.0f); o.y = t * t * inv;
        t = fmaxf(fmaf(z[4 * k + 2], 0.5f, cF), 0.0f); o.z = t * t * inv;
        t = fmaxf(fmaf(z[4 * k + 3], 0.5f, cF), 0.0f); o.w = t * t * inv;
        __builtin_nontemporal_store(o, reinterpret_cast<f4*>(orow + (size_t)(k * 64 + lane) * 4));
    }
}

extern "C" void kernel_launch(void* const* d_in, const int* in_sizes, int n_in,
                              void* d_out, int out_size, void* d_ws, size_t ws_size,
                              hipStream_t stream) {
    const float* x = (const float*)d_in[0];
    float* out = (float*)d_out;
    const int rows = in_sizes[0] / ROWLEN;  // 16384
    const int blocks = (rows + RPB - 1) / RPB;
    entmax15_kernel<<<blocks, 256, 0, stream>>>(x, out, rows);
}